// Round 1
// baseline (243.371 us; speedup 1.0000x reference)
//
#include <hip/hip_runtime.h>

// Problem constants (fixed by the reference)
#define BATCH   262144
#define DDIM    128
#define GRID    2048
#define NITER   8            // BATCH / (GRID * 4 waves * 4 rows/wave/iter)
// blocks: j%3==0 dense, j%3==1 diagonal, j%3==2 lowrank; k = j/3.

// --- cross-lane helpers: VALU-pipe DPP instead of ds_bpermute shuffles ---
// quad_perm codes: xor1 = [1,0,3,2] = 0xB1; xor2 = [2,3,0,1] = 0x4E;
// xor3 = [3,2,1,0] = 0x1B. row_half_mirror = 0x141 (lane^7 pairing),
// row_mirror = 0x140 (lane^15 pairing).
template <int CTRL>
__device__ __forceinline__ float fdpp(float v) {
    int i = __builtin_bit_cast(int, v);
    i = __builtin_amdgcn_mov_dpp(i, CTRL, 0xF, 0xF, true);
    return __builtin_bit_cast(float, i);
}
// xor16 within each 32-lane half: ds_swizzle BitMode (16<<10)|0x1F
__device__ __forceinline__ float fswz16(float v) {
    int i = __builtin_bit_cast(int, v);
    i = __builtin_amdgcn_ds_swizzle(i, 0x401F);
    return __builtin_bit_cast(float, i);
}

__global__ __launch_bounds__(256, 3) void bdla_kernel(
    const float* __restrict__ x,
    const float* __restrict__ Wd,   // [3,16,16]  W[k][o][d]
    const float* __restrict__ sd,   // [3,16]
    const float* __restrict__ U,    // [2,16,4]
    const float* __restrict__ V,    // [2,16,4]
    float* __restrict__ out)
{
    __shared__ float lds[1072];     // 768 Wd | 48 sd | 128 U | 128 V
    const int tid = threadIdx.x;
    for (int i = tid; i < 768; i += 256) lds[i] = Wd[i];
    if (tid < 48)  lds[768 + tid] = sd[tid];
    if (tid < 128) lds[816 + tid] = U[tid];
    if (tid < 128) lds[944 + tid] = V[tid];
    __syncthreads();

    const int lane   = tid & 63;
    const int lane32 = lane & 31;
    const int half   = lane >> 5;      // which row of the wave's pair
    const int j      = lane32 >> 2;    // block id 0..7
    const int sub    = lane32 & 3;     // quarter within block (4 outputs)
    const int mode   = j % 3;          // 0 dense, 1 diag, 2 lowrank
    const int k      = j / 3;

    // A[oo][m*4+c]: weight applied to g[m*4+c] = dpp_xor(xv.c, m),
    // i.e. block-input element d = (sub^m)*4 + c.
    float A[4][16];
    if (mode == 0) {
        const float* w = &lds[k * 256];
#pragma unroll
        for (int oo = 0; oo < 4; ++oo) {
            const int o = sub * 4 + oo;
#pragma unroll
            for (int m = 0; m < 4; ++m)
#pragma unroll
                for (int c = 0; c < 4; ++c)
                    A[oo][m * 4 + c] = w[o * 16 + ((sub ^ m) * 4 + c)];
        }
    } else if (mode == 1) {
        const float* s = &lds[768 + k * 16];
#pragma unroll
        for (int oo = 0; oo < 4; ++oo)
#pragma unroll
            for (int m = 0; m < 4; ++m)
#pragma unroll
                for (int c = 0; c < 4; ++c)
                    A[oo][m * 4 + c] = (m == 0 && c == oo) ? s[sub * 4 + oo] : 0.0f;
    } else {
        const float* u = &lds[816 + k * 64];
        const float* v = &lds[944 + k * 64];
#pragma unroll
        for (int oo = 0; oo < 4; ++oo) {
            const int o = sub * 4 + oo;
#pragma unroll
            for (int m = 0; m < 4; ++m)
#pragma unroll
                for (int c = 0; c < 4; ++c) {
                    const int d = (sub ^ m) * 4 + c;
                    float acc = 0.0f;
#pragma unroll
                    for (int r = 0; r < 4; ++r)
                        acc += u[o * 4 + r] * v[d * 4 + r];
                    A[oo][m * 4 + c] = acc;
                }
        }
    }

    // Pin A into VGPRs: opaque asm def prevents the compiler from
    // rematerializing A via per-iteration LDS reads (R1: VGPR=64 proved it
    // was reloading A from LDS in the hot loop -> 5.8M bank-conflict cycles).
#pragma unroll
    for (int oo = 0; oo < 4; ++oo)
#pragma unroll
        for (int t = 0; t < 16; ++t)
            asm volatile("" : "+v"(A[oo][t]));

    // Row mapping: wave gw, iter it -> rows it*32768 + gw*4 + {half, 2+half}
    const int gw = blockIdx.x * 4 + (tid >> 6);
    const float* xbase = x   + (size_t)(gw * 4 + half) * DDIM + lane32 * 4;
    float*       obase = out + (size_t)(gw * 4 + half) * DDIM + lane32 * 4;
    const size_t istep = (size_t)(GRID * 4 * 4) * DDIM;   // floats per iter step

    // depth-2 software pipeline
    float4 a0 = *(const float4*)(xbase);
    float4 b0 = *(const float4*)(xbase + 2 * DDIM);
    float4 a1 = *(const float4*)(xbase + istep);
    float4 b1 = *(const float4*)(xbase + istep + 2 * DDIM);

#pragma unroll
    for (int it = 0; it < NITER; ++it) {
        float4 a2, b2;
        if (it + 2 < NITER) {
            a2 = *(const float4*)(xbase + (size_t)(it + 2) * istep);
            b2 = *(const float4*)(xbase + (size_t)(it + 2) * istep + 2 * DDIM);
        }

        // gather the 16 inputs of this lane's block for both rows.
        // All cross-lane moves are intra-quad -> quad_perm DPP (VALU pipe,
        // no lgkmcnt), replacing ds_bpermute-lowered __shfl_xor.
        float ga[16], gb[16];
        ga[0] = a0.x; ga[1] = a0.y; ga[2] = a0.z; ga[3] = a0.w;
        gb[0] = b0.x; gb[1] = b0.y; gb[2] = b0.z; gb[3] = b0.w;
        // m = 1 (lane^1)
        ga[4]  = fdpp<0xB1>(a0.x); ga[5]  = fdpp<0xB1>(a0.y);
        ga[6]  = fdpp<0xB1>(a0.z); ga[7]  = fdpp<0xB1>(a0.w);
        gb[4]  = fdpp<0xB1>(b0.x); gb[5]  = fdpp<0xB1>(b0.y);
        gb[6]  = fdpp<0xB1>(b0.z); gb[7]  = fdpp<0xB1>(b0.w);
        // m = 2 (lane^2)
        ga[8]  = fdpp<0x4E>(a0.x); ga[9]  = fdpp<0x4E>(a0.y);
        ga[10] = fdpp<0x4E>(a0.z); ga[11] = fdpp<0x4E>(a0.w);
        gb[8]  = fdpp<0x4E>(b0.x); gb[9]  = fdpp<0x4E>(b0.y);
        gb[10] = fdpp<0x4E>(b0.z); gb[11] = fdpp<0x4E>(b0.w);
        // m = 3 (lane^3)
        ga[12] = fdpp<0x1B>(a0.x); ga[13] = fdpp<0x1B>(a0.y);
        ga[14] = fdpp<0x1B>(a0.z); ga[15] = fdpp<0x1B>(a0.w);
        gb[12] = fdpp<0x1B>(b0.x); gb[13] = fdpp<0x1B>(b0.y);
        gb[14] = fdpp<0x1B>(b0.z); gb[15] = fdpp<0x1B>(b0.w);

        float ya0 = 0.f, ya1 = 0.f, ya2 = 0.f, ya3 = 0.f;
        float yb0 = 0.f, yb1 = 0.f, yb2 = 0.f, yb3 = 0.f;
#pragma unroll
        for (int t = 0; t < 16; ++t) {
            ya0 = fmaf(A[0][t], ga[t], ya0);
            ya1 = fmaf(A[1][t], ga[t], ya1);
            ya2 = fmaf(A[2][t], ga[t], ya2);
            ya3 = fmaf(A[3][t], ga[t], ya3);
            yb0 = fmaf(A[0][t], gb[t], yb0);
            yb1 = fmaf(A[1][t], gb[t], yb1);
            yb2 = fmaf(A[2][t], gb[t], yb2);
            yb3 = fmaf(A[3][t], gb[t], yb3);
        }

        // L2 norm across each row's 32 lanes.
        // Allreduce via involutive pairings, all on the VALU pipe except the
        // final xor16: xor1, xor2 (quad_perm), lane^7 (row_half_mirror),
        // lane^15 (row_mirror), then one ds_swizzle for lane^16.
        float ssa = ya0 * ya0 + ya1 * ya1 + ya2 * ya2 + ya3 * ya3;
        float ssb = yb0 * yb0 + yb1 * yb1 + yb2 * yb2 + yb3 * yb3;
        ssa += fdpp<0xB1>(ssa);  ssb += fdpp<0xB1>(ssb);   // + lane^1
        ssa += fdpp<0x4E>(ssa);  ssb += fdpp<0x4E>(ssb);   // + lane^2 -> quad sum
        ssa += fdpp<0x141>(ssa); ssb += fdpp<0x141>(ssb);  // + lane^7 -> 8-sum
        ssa += fdpp<0x140>(ssa); ssb += fdpp<0x140>(ssb);  // + lane^15 -> 16-sum
        ssa += fswz16(ssa);      ssb += fswz16(ssb);       // + lane^16 -> 32-sum
        const float inva = 1.0f / (sqrtf(ssa) + 1e-8f);
        const float invb = 1.0f / (sqrtf(ssb) + 1e-8f);

        float4 yva, yvb;
        yva.x = ya0 * inva; yva.y = ya1 * inva; yva.z = ya2 * inva; yva.w = ya3 * inva;
        yvb.x = yb0 * invb; yvb.y = yb1 * invb; yvb.z = yb2 * invb; yvb.w = yb3 * invb;
        *(float4*)(obase + (size_t)it * istep)            = yva;
        *(float4*)(obase + (size_t)it * istep + 2 * DDIM) = yvb;

        a0 = a1; b0 = b1; a1 = a2; b1 = b2;
    }
}

extern "C" void kernel_launch(void* const* d_in, const int* in_sizes, int n_in,
                              void* d_out, int out_size, void* d_ws, size_t ws_size,
                              hipStream_t stream) {
    const float* x  = (const float*)d_in[0];
    const float* Wd = (const float*)d_in[1];
    const float* sd = (const float*)d_in[2];
    const float* U  = (const float*)d_in[3];
    const float* V  = (const float*)d_in[4];
    float* out = (float*)d_out;
    (void)in_sizes; (void)n_in; (void)out_size; (void)d_ws; (void)ws_size;

    dim3 grid(GRID), block(256);
    hipLaunchKernelGGL(bdla_kernel, grid, block, 0, stream, x, Wd, sd, U, V, out);
}